// Round 3
// baseline (219.318 us; speedup 1.0000x reference)
//
#include <hip/hip_runtime.h>
#include <hip/hip_bf16.h>

// Problem constants (DeformableNCC)
constexpr int B_ = 64, K_ = 32, T_ = 1280, C_ = 16, E_ = 64;
constexpr int CC_ = 32, POOL_ = 10, TB_ = 128;           // conv channels, pool bins, t per bin
constexpr long long OUT_WARPED = (long long)B_ * K_ * T_ * C_;  // 41,943,040

// Native clang vector for nontemporal builtins (HIP float4 is a class type
// that __builtin_nontemporal_store rejects).
typedef float floatx4 __attribute__((ext_vector_type(4)));

// ---------------------------------------------------------------------------
// Kernel A: Conv1d(k=5,pad=2) + ReLU + avg-pool(128) for one (b, pool-bin).
// grid = B*POOL blocks x 256 threads. Output: pooled[b*320 + oc*10 + p].
// Mapping: oc = tid&31 (fast), tsub = tid>>5. A wave's 32 low lanes all read
// the SAME xs address (broadcast, free); only 2 distinct addresses per wave
// (2-way aliasing = free per m136).
// ---------------------------------------------------------------------------
__global__ __launch_bounds__(256) void conv_pool_k(
    const float* __restrict__ x,       // [B,T,C]
    const float* __restrict__ conv_w,  // [32,16,5]
    const float* __restrict__ conv_b,  // [32]
    float* __restrict__ pooled)        // [B,320]  (flatten order oc*10+p)
{
    const int blk = blockIdx.x;
    const int b = blk / POOL_;
    const int p = blk % POOL_;
    const int tid = threadIdx.x;

    // xs rows r = 0..131 correspond to global t = p*128 - 2 + r; stride 20
    // floats keeps rows 16B-aligned.
    __shared__ float xs[132 * 20];
    // wt[oc*84 + kt*16 + ic]: transposed weights, 16B-aligned rows.
    __shared__ float wt[32 * 84];
    __shared__ float part[256];

    // Stage transposed weights: conv_w flat [oc][ic][kt]
    for (int f = tid; f < CC_ * C_ * 5; f += 256) {
        int oc = f / 80, r = f % 80, ic = r / 5, kt = r % 5;
        wt[oc * 84 + kt * 16 + ic] = conv_w[f];
    }
    // Stage x window (zero padded outside [0,T))
    const float4* x4 = (const float4*)(x + (size_t)b * T_ * C_);
    for (int f = tid; f < 132 * 4; f += 256) {
        int row = f >> 2, c4 = f & 3;
        int t = p * TB_ - 2 + row;
        float4 v = make_float4(0.f, 0.f, 0.f, 0.f);
        if (t >= 0 && t < T_) v = x4[t * 4 + c4];
        *(float4*)(&xs[row * 20 + c4 * 4]) = v;
    }
    __syncthreads();

    const int oc = tid & 31;    // fast within wave -> xs broadcast across lanes
    const int tsub = tid >> 5;  // 0..7

    // Hoist weights to registers: 5 kt x 4 float4 = 80 VGPRs
    float4 w[5][4];
#pragma unroll
    for (int kt = 0; kt < 5; ++kt)
#pragma unroll
        for (int c4 = 0; c4 < 4; ++c4)
            w[kt][c4] = *(const float4*)(&wt[oc * 84 + kt * 16 + c4 * 4]);
    const float bias = conv_b[oc];

    const int base = tsub * 16;  // first xs row this thread needs
    float4 win[5][4];
#pragma unroll
    for (int r = 0; r < 4; ++r)
#pragma unroll
        for (int c4 = 0; c4 < 4; ++c4)
            win[r][c4] = *(const float4*)(&xs[(base + r) * 20 + c4 * 4]);

    float local = 0.f;
#pragma unroll
    for (int jj = 0; jj < 16; ++jj) {
        const int ld = (jj + 4) % 5;
#pragma unroll
        for (int c4 = 0; c4 < 4; ++c4)
            win[ld][c4] = *(const float4*)(&xs[(base + jj + 4) * 20 + c4 * 4]);
        float acc = bias;
#pragma unroll
        for (int kt = 0; kt < 5; ++kt) {
            const float4* xv = win[(jj + kt) % 5];
#pragma unroll
            for (int c4 = 0; c4 < 4; ++c4) {
                acc += xv[c4].x * w[kt][c4].x;
                acc += xv[c4].y * w[kt][c4].y;
                acc += xv[c4].z * w[kt][c4].z;
                acc += xv[c4].w * w[kt][c4].w;
            }
        }
        local += fmaxf(acc, 0.f);
    }

    part[tid] = local;  // layout [tsub][oc]
    __syncthreads();
    if (tid < CC_) {
        float s = 0.f;
#pragma unroll
        for (int i = 0; i < 8; ++i) s += part[i * 32 + tid];
        pooled[b * (CC_ * POOL_) + tid * POOL_ + p] = s * (1.f / 128.f);
    }
}

// ---------------------------------------------------------------------------
// Kernel B: embed = relu(pooled @ lin_w.T + lin_b); warp/off heads.
// grid = B blocks x 64 threads (one wave).
// ---------------------------------------------------------------------------
__global__ __launch_bounds__(64) void heads_k(
    const float* __restrict__ pooled,  // [B,320]
    const float* __restrict__ lin_w,   // [64,320]
    const float* __restrict__ lin_b,   // [64]
    const float* __restrict__ warp_W,  // [32,64]
    const float* __restrict__ warp_b,  // [32]
    const float* __restrict__ off_W,   // [32,64]
    const float* __restrict__ off_b,   // [32]
    float* __restrict__ warp_s,        // [B*K] scratch
    float* __restrict__ off_s,         // [B*K] scratch
    float* __restrict__ out_tail)      // d_out + OUT_WARPED
{
    const int b = blockIdx.x;
    const int tid = threadIdx.x;
    __shared__ float4 ps4[80];
    __shared__ float emb[64];

    const float4* pin = (const float4*)(pooled + (size_t)b * 320);
    for (int i = tid; i < 80; i += 64) ps4[i] = pin[i];
    __syncthreads();

    // embed[tid]
    float acc = lin_b[tid];
    const float4* lw4 = (const float4*)(lin_w + (size_t)tid * 320);
#pragma unroll 4
    for (int i = 0; i < 80; ++i) {
        float4 a = ps4[i], w = lw4[i];
        acc += a.x * w.x + a.y * w.y + a.z * w.z + a.w * w.w;
    }
    emb[tid] = fmaxf(acc, 0.f);
    __syncthreads();

    const int k = tid & 31;
    const float* W = (tid < 32) ? warp_W : off_W;
    const float* bb = (tid < 32) ? warp_b : off_b;
    float a2 = bb[k];
#pragma unroll 8
    for (int e = 0; e < E_; ++e) a2 += emb[e] * W[k * E_ + e];

    if (tid < 32) {
        warp_s[b * K_ + k] = a2;
        out_tail[b * K_ + k] = a2;           // warp output [B,K,1]
    } else {
        off_s[b * K_ + k] = a2;
        out_tail[B_ * K_ + b * K_ + k] = a2; // off output [B,K,1]
    }
}

// ---------------------------------------------------------------------------
// Kernel C: warped[b,k,t,:] = lerp(proto[k,i0,:], proto[k,i1,:]) + off.
// One block per (b,k): 2048 blocks x 256 threads, 8 blocks/CU. warp/off are
// block-uniform (loaded once). Each thread stores 20 float4s; every store
// instruction is lane-contiguous (1 KiB/wave). Nontemporal stores keep the
// 168 MB write stream from churning prototypes out of L2.
// ---------------------------------------------------------------------------
__global__ __launch_bounds__(256) void warp_interp_k(
    const float* __restrict__ proto,   // [K,T,C]
    const float* __restrict__ warp_s,  // [B*K]
    const float* __restrict__ off_s,   // [B*K]
    float* __restrict__ out)           // [B,K,T,C]
{
    const int bk = blockIdx.x;         // b*K + k
    const int k = bk & (K_ - 1);
    const int tid = threadIdx.x;

    const float wv = warp_s[bk];
    const float ov = off_s[bk];

    const floatx4* pk = (const floatx4*)proto + (size_t)k * T_ * 4;
    floatx4* ob = (floatx4*)out + (size_t)bk * T_ * 4;

#pragma unroll 4
    for (int m = 0; m < 20; ++m) {
        const int fi = m * 256 + tid;       // 0..5119 float4 index in this bk
        const int t = fi >> 2;
        const int q = fi & 3;

        float idx = fminf(fmaxf((float)t - wv, 0.f), (float)(T_ - 1));
        const float f0 = floorf(idx);
        const int i0 = (int)f0;
        const int i1 = min(i0 + 1, T_ - 1);
        const float fr = idx - f0;
        const float omf = 1.f - fr;

        const floatx4 g0 = pk[i0 * 4 + q];
        const floatx4 g1 = pk[i1 * 4 + q];

        floatx4 r = (g0 + ov) * omf + (g1 + ov) * fr;
        __builtin_nontemporal_store(r, &ob[fi]);
    }
}

// ---------------------------------------------------------------------------
extern "C" void kernel_launch(void* const* d_in, const int* in_sizes, int n_in,
                              void* d_out, int out_size, void* d_ws, size_t ws_size,
                              hipStream_t stream) {
    const float* x       = (const float*)d_in[0];
    const float* proto   = (const float*)d_in[1];
    const float* conv_w  = (const float*)d_in[2];
    const float* conv_b  = (const float*)d_in[3];
    const float* lin_w   = (const float*)d_in[4];
    const float* lin_b   = (const float*)d_in[5];
    const float* warp_W  = (const float*)d_in[6];
    const float* warp_b  = (const float*)d_in[7];
    const float* off_W   = (const float*)d_in[8];
    const float* off_b   = (const float*)d_in[9];

    float* out = (float*)d_out;
    float* ws = (float*)d_ws;
    float* pooled = ws;                       // 64*320 = 20480 floats
    float* warp_s = ws + 20480;               // 2048 floats
    float* off_s  = ws + 20480 + 2048;        // 2048 floats

    conv_pool_k<<<dim3(B_ * POOL_), dim3(256), 0, stream>>>(x, conv_w, conv_b, pooled);
    heads_k<<<dim3(B_), dim3(64), 0, stream>>>(pooled, lin_w, lin_b, warp_W, warp_b,
                                               off_W, off_b, warp_s, off_s,
                                               out + OUT_WARPED);
    warp_interp_k<<<dim3(B_ * K_), dim3(256), 0, stream>>>(
        proto, warp_s, off_s, out);
}

// Round 4
// 214.823 us; speedup vs baseline: 1.0209x; 1.0209x over previous
//
#include <hip/hip_runtime.h>
#include <hip/hip_bf16.h>

// Problem constants (DeformableNCC)
constexpr int B_ = 64, K_ = 32, T_ = 1280, C_ = 16, E_ = 64;
constexpr int CC_ = 32, POOL_ = 10, TB_ = 128;           // conv channels, pool bins, t per bin
constexpr long long OUT_WARPED = (long long)B_ * K_ * T_ * C_;  // 41,943,040

// Native clang vector for nontemporal builtins (HIP float4 is a class type
// that __builtin_nontemporal_store rejects).
typedef float floatx4 __attribute__((ext_vector_type(4)));

// ---------------------------------------------------------------------------
// Kernel A: Conv1d(k=5,pad=2) + ReLU + avg-pool(128) for one (b, pool-bin).
// grid = B*POOL blocks x 256 threads. Output: pooled[b*320 + oc*10 + p].
// Mapping: oc = tid&31 (fast) -> xs reads broadcast across the wave's 32
// low lanes (free); only 2 distinct LDS addresses per wave (2-way = free).
// ---------------------------------------------------------------------------
__global__ __launch_bounds__(256) void conv_pool_k(
    const float* __restrict__ x,       // [B,T,C]
    const float* __restrict__ conv_w,  // [32,16,5]
    const float* __restrict__ conv_b,  // [32]
    float* __restrict__ pooled)        // [B,320]  (flatten order oc*10+p)
{
    const int blk = blockIdx.x;
    const int b = blk / POOL_;
    const int p = blk % POOL_;
    const int tid = threadIdx.x;

    __shared__ float xs[132 * 20];   // rows 16B-aligned, stride 20 floats
    __shared__ float wt[32 * 84];    // wt[oc*84 + kt*16 + ic]
    __shared__ float part[256];

    // Stage transposed weights: conv_w flat [oc][ic][kt]
    for (int f = tid; f < CC_ * C_ * 5; f += 256) {
        int oc = f / 80, r = f % 80, ic = r / 5, kt = r % 5;
        wt[oc * 84 + kt * 16 + ic] = conv_w[f];
    }
    // Stage x window (zero padded outside [0,T))
    const float4* x4 = (const float4*)(x + (size_t)b * T_ * C_);
    for (int f = tid; f < 132 * 4; f += 256) {
        int row = f >> 2, c4 = f & 3;
        int t = p * TB_ - 2 + row;
        float4 v = make_float4(0.f, 0.f, 0.f, 0.f);
        if (t >= 0 && t < T_) v = x4[t * 4 + c4];
        *(float4*)(&xs[row * 20 + c4 * 4]) = v;
    }
    __syncthreads();

    const int oc = tid & 31;    // fast within wave -> xs broadcast across lanes
    const int tsub = tid >> 5;  // 0..7

    // Hoist weights to registers: 5 kt x 4 float4 = 80 VGPRs
    float4 w[5][4];
#pragma unroll
    for (int kt = 0; kt < 5; ++kt)
#pragma unroll
        for (int c4 = 0; c4 < 4; ++c4)
            w[kt][c4] = *(const float4*)(&wt[oc * 84 + kt * 16 + c4 * 4]);
    const float bias = conv_b[oc];

    const int base = tsub * 16;  // first xs row this thread needs
    float4 win[5][4];
#pragma unroll
    for (int r = 0; r < 4; ++r)
#pragma unroll
        for (int c4 = 0; c4 < 4; ++c4)
            win[r][c4] = *(const float4*)(&xs[(base + r) * 20 + c4 * 4]);

    float local = 0.f;
#pragma unroll
    for (int jj = 0; jj < 16; ++jj) {
        const int ld = (jj + 4) % 5;
#pragma unroll
        for (int c4 = 0; c4 < 4; ++c4)
            win[ld][c4] = *(const float4*)(&xs[(base + jj + 4) * 20 + c4 * 4]);
        float acc = bias;
#pragma unroll
        for (int kt = 0; kt < 5; ++kt) {
            const float4* xv = win[(jj + kt) % 5];
#pragma unroll
            for (int c4 = 0; c4 < 4; ++c4) {
                acc += xv[c4].x * w[kt][c4].x;
                acc += xv[c4].y * w[kt][c4].y;
                acc += xv[c4].z * w[kt][c4].z;
                acc += xv[c4].w * w[kt][c4].w;
            }
        }
        local += fmaxf(acc, 0.f);
    }

    part[tid] = local;  // layout [tsub][oc]
    __syncthreads();
    if (tid < CC_) {
        float s = 0.f;
#pragma unroll
        for (int i = 0; i < 8; ++i) s += part[i * 32 + tid];
        pooled[b * (CC_ * POOL_) + tid * POOL_ + p] = s * (1.f / 128.f);
    }
}

// ---------------------------------------------------------------------------
// Kernel B: embed = relu(pooled @ lin_w.T + lin_b); warp/off heads.
// grid = B blocks x 128 threads (2 waves: wave0 does embed+warp-head,
// wave1 helps embed then does off-head -> shorter serial tail).
// ---------------------------------------------------------------------------
__global__ __launch_bounds__(128) void heads_k(
    const float* __restrict__ pooled,  // [B,320]
    const float* __restrict__ lin_w,   // [64,320]
    const float* __restrict__ lin_b,   // [64]
    const float* __restrict__ warp_W,  // [32,64]
    const float* __restrict__ warp_b,  // [32]
    const float* __restrict__ off_W,   // [32,64]
    const float* __restrict__ off_b,   // [32]
    float* __restrict__ warp_s,        // [B*K] scratch
    float* __restrict__ off_s,         // [B*K] scratch
    float* __restrict__ out_tail)      // d_out + OUT_WARPED
{
    const int b = blockIdx.x;
    const int tid = threadIdx.x;
    __shared__ float4 ps4[80];
    __shared__ float emb[64];

    const float4* pin = (const float4*)(pooled + (size_t)b * 320);
    if (tid < 80) ps4[tid] = pin[tid];
    __syncthreads();

    // embed: 128 threads, 2 threads per output element (split the 80-dot)
    const int e = tid >> 1;        // 0..63
    const int half = tid & 1;      // 0..1
    float acc = 0.f;
    const float4* lw4 = (const float4*)(lin_w + (size_t)e * 320) + half * 40;
    const float4* pp = ps4 + half * 40;
#pragma unroll 8
    for (int i = 0; i < 40; ++i) {
        float4 a = pp[i], w = lw4[i];
        acc += a.x * w.x + a.y * w.y + a.z * w.z + a.w * w.w;
    }
    acc += __shfl_xor(acc, 1);
    if (half == 0) emb[e] = fmaxf(acc + lin_b[e], 0.f);
    __syncthreads();

    // heads: tid 0..31 -> warp head, 64..95 -> off head (one per wave)
    const int k = tid & 31;
    const bool is_warp = (tid < 64);
    if ((tid & 63) < 32) {
        const float* W = is_warp ? warp_W : off_W;
        float a2 = (is_warp ? warp_b : off_b)[k];
#pragma unroll 8
        for (int ee = 0; ee < E_; ++ee) a2 += emb[ee] * W[k * E_ + ee];
        if (is_warp) {
            warp_s[b * K_ + k] = a2;
            out_tail[b * K_ + k] = a2;           // warp output [B,K,1]
        } else {
            off_s[b * K_ + k] = a2;
            out_tail[B_ * K_ + b * K_ + k] = a2; // off output [B,K,1]
        }
    }
}

// ---------------------------------------------------------------------------
// Kernel C: warped[b,k,t,:] = lerp(proto[k,i0,:]+off, proto[k,i1,:]+off).
// One block per (b,k): 2048 blocks x 256 threads (8/CU). q = tid&3 and
// t = m*64 + tid>>2 are strength-reduced out of the loop; per-iter work is
// clamp/floor/lerp + one nontemporal 16B store (lane-contiguous 1 KiB/wave).
// ---------------------------------------------------------------------------
__global__ __launch_bounds__(256) void warp_interp_k(
    const float* __restrict__ proto,   // [K,T,C]
    const float* __restrict__ warp_s,  // [B*K]
    const float* __restrict__ off_s,   // [B*K]
    float* __restrict__ out)           // [B,K,T,C]
{
    const int bk = blockIdx.x;         // b*K + k
    const int k = bk & (K_ - 1);
    const int tid = threadIdx.x;

    const float wv = warp_s[bk];
    const float ov = off_s[bk];

    const int q = tid & 3;             // constant per thread (256 % 4 == 0)
    const floatx4* pq = (const floatx4*)proto + (size_t)k * T_ * 4 + q;
    floatx4* op = (floatx4*)out + (size_t)bk * T_ * 4 + tid;

    float tf = (float)(tid >> 2);      // t for m=0; += 64 per iteration
    const float tmax = (float)(T_ - 1);

#pragma unroll 4
    for (int m = 0; m < 20; ++m, tf += 64.f, op += 256) {
        float idx = fminf(fmaxf(tf - wv, 0.f), tmax);
        const float f0 = floorf(idx);
        const int i0 = (int)f0;
        const int i1 = min(i0 + 1, T_ - 1);
        const float fr = idx - f0;
        const float omf = 1.f - fr;

        const floatx4 g0 = pq[i0 * 4];
        const floatx4 g1 = pq[i1 * 4];

        floatx4 r = (g0 + ov) * omf + (g1 + ov) * fr;
        __builtin_nontemporal_store(r, op);
    }
}

// ---------------------------------------------------------------------------
extern "C" void kernel_launch(void* const* d_in, const int* in_sizes, int n_in,
                              void* d_out, int out_size, void* d_ws, size_t ws_size,
                              hipStream_t stream) {
    const float* x       = (const float*)d_in[0];
    const float* proto   = (const float*)d_in[1];
    const float* conv_w  = (const float*)d_in[2];
    const float* conv_b  = (const float*)d_in[3];
    const float* lin_w   = (const float*)d_in[4];
    const float* lin_b   = (const float*)d_in[5];
    const float* warp_W  = (const float*)d_in[6];
    const float* warp_b  = (const float*)d_in[7];
    const float* off_W   = (const float*)d_in[8];
    const float* off_b   = (const float*)d_in[9];

    float* out = (float*)d_out;
    float* ws = (float*)d_ws;
    float* pooled = ws;                       // 64*320 = 20480 floats
    float* warp_s = ws + 20480;               // 2048 floats
    float* off_s  = ws + 20480 + 2048;        // 2048 floats

    conv_pool_k<<<dim3(B_ * POOL_), dim3(256), 0, stream>>>(x, conv_w, conv_b, pooled);
    heads_k<<<dim3(B_), dim3(128), 0, stream>>>(pooled, lin_w, lin_b, warp_W, warp_b,
                                                off_W, off_b, warp_s, off_s,
                                                out + OUT_WARPED);
    warp_interp_k<<<dim3(B_ * K_), dim3(256), 0, stream>>>(
        proto, warp_s, off_s, out);
}